// Round 1
// baseline (31255.573 us; speedup 1.0000x reference)
//
#include <hip/hip_runtime.h>

#define B_ 64
#define N_ 512
#define H_ 64

// ---------------------------------------------------------------------------
// Build Bmat (512 x 2048): columns [S0^T | (S0^2)^T | S1^T | (S1^2)^T]
// Bmat[m*2048 + t*512 + n] = M_t[n, m]
// ---------------------------------------------------------------------------
__global__ __launch_bounds__(256) void bmat_copy_k(const float* __restrict__ S,
                                                   float* __restrict__ Bmat) {
  int idx = blockIdx.x * blockDim.x + threadIdx.x;
  if (idx >= 2 * N_ * N_) return;
  int n = idx & 511;
  int m = (idx >> 9) & 511;
  int s = idx >> 18;
  // t = 0 for s=0 (cols 0..511), t = 2 for s=1 (cols 1024..1535)
  Bmat[m * 2048 + s * 1024 + n] = S[(s * N_ + n) * N_ + m];
}

__global__ __launch_bounds__(256) void bmat_sq_k(const float* __restrict__ S,
                                                 float* __restrict__ Bmat) {
  int s = blockIdx.z;
  const float* Ss = S + s * N_ * N_;
  __shared__ float Ta[16][17], Tb[16][17];
  int n = blockIdx.y * 16 + threadIdx.y;
  int m = blockIdx.x * 16 + threadIdx.x;
  float acc = 0.f;
  for (int p0 = 0; p0 < N_; p0 += 16) {
    Ta[threadIdx.y][threadIdx.x] = Ss[n * N_ + p0 + threadIdx.x];
    Tb[threadIdx.y][threadIdx.x] = Ss[(p0 + threadIdx.y) * N_ + m];
    __syncthreads();
#pragma unroll
    for (int pp = 0; pp < 16; ++pp)
      acc = fmaf(Ta[threadIdx.y][pp], Tb[pp][threadIdx.x], acc);
    __syncthreads();
  }
  // squares go at cols (s*1024 + 512)
  Bmat[m * 2048 + s * 1024 + 512 + n] = acc;
}

// ---------------------------------------------------------------------------
// Pack z = concat([x, h * (r?)], axis=channel) into ZF channels [0, C)
// ZF layout: (B, CT, 512), z part in channels [0, C), C = Cx + 64, CT = 5C
// xmode 0: x from inputs gather at time t; xmode 1: x contiguous (B,Cx,512)
// r (nullable) points at RU (B,128,512), r = channels [0,64)
// ---------------------------------------------------------------------------
__global__ __launch_bounds__(256) void pack_z_k(float* __restrict__ ZF, int CT, int Cx,
                                                const float* __restrict__ xsrc, int xmode,
                                                int t, const float* __restrict__ h,
                                                const float* __restrict__ r) {
  int C = Cx + H_;
  int idx = blockIdx.x * blockDim.x + threadIdx.x;
  int total = B_ * C * N_;
  if (idx >= total) return;
  int n = idx & 511;
  int c = (idx >> 9) % C;
  int b = idx / (C * N_);
  float v;
  if (c < Cx) {
    if (xmode == 0) v = xsrc[((b * Cx + c) * N_ + n) * 12 + t];
    else            v = xsrc[(b * Cx + c) * N_ + n];
  } else {
    int j = c - Cx;
    v = h[(b * H_ + j) * N_ + n];
    if (r) v *= r[(b * 128 + j) * N_ + n];
  }
  ZF[((size_t)(b * CT + c)) * N_ + n] = v;
}

// ---------------------------------------------------------------------------
// Diffusion GEMM: for each b, Out(C x 2048) = Z(C x 512) @ Bmat(512 x 2048)
// Input rows: ZF[b, c, :], output written to ZF[b, (1+t)*C + c, n], t = j>>9
// 64x64 tile, K-chunk 16, 256 threads, 4x4 microtile.
// ---------------------------------------------------------------------------
__global__ __launch_bounds__(256) void gemm_diff_k(const float* __restrict__ Bm,
                                                   float* ZF, int C, int CT) {
  __shared__ float As[16][68];
  __shared__ float Bs[16][68];
  int b = blockIdx.z;
  int c0 = blockIdx.x * 64;
  int j0 = blockIdx.y * 64;
  int tid = threadIdx.x;
  int tx = tid & 15, ty = tid >> 4;
  const float* Ab = ZF + (size_t)b * CT * N_;
  float acc[4][4] = {};
  for (int k0 = 0; k0 < N_; k0 += 16) {
#pragma unroll
    for (int i = 0; i < 4; ++i) {
      int c = c0 + ty + 16 * i;
      As[tx][ty + 16 * i] = (c < C) ? Ab[c * N_ + k0 + tx] : 0.f;
    }
#pragma unroll
    for (int i = 0; i < 4; ++i) {
      int ml = (tid >> 6) + 4 * i;
      Bs[ml][tid & 63] = Bm[(k0 + ml) * 2048 + j0 + (tid & 63)];
    }
    __syncthreads();
#pragma unroll
    for (int kk = 0; kk < 16; ++kk) {
      float a[4], bb[4];
#pragma unroll
      for (int i = 0; i < 4; ++i) a[i] = As[kk][ty * 4 + i];
#pragma unroll
      for (int i = 0; i < 4; ++i) bb[i] = Bs[kk][tx * 4 + i];
#pragma unroll
      for (int i = 0; i < 4; ++i)
#pragma unroll
        for (int jj = 0; jj < 4; ++jj)
          acc[i][jj] = fmaf(a[i], bb[jj], acc[i][jj]);
    }
    __syncthreads();
  }
#pragma unroll
  for (int i = 0; i < 4; ++i) {
    int c = c0 + ty * 4 + i;
    if (c >= C) continue;
#pragma unroll
    for (int jj = 0; jj < 4; ++jj) {
      int j = j0 + tx * 4 + jj;
      int t = j >> 9, n = j & 511;
      ZF[((size_t)(b * CT + (1 + t) * C + c)) * N_ + n] = acc[i][jj];
    }
  }
}

// ---------------------------------------------------------------------------
// Projection GEMM: for each b, Out(Dout x 512) = W^T(Dout x CT) @ ZF[b](CT x 512)
// + bias, + activation (act 0: sigmoid, act 1: tanh). W is (CT x Dout) row-major.
// ---------------------------------------------------------------------------
__global__ __launch_bounds__(256) void gemm_proj_k(const float* __restrict__ W,
                                                   const float* __restrict__ bias,
                                                   const float* __restrict__ ZF,
                                                   float* __restrict__ Out,
                                                   int CT, int Dout, int act) {
  __shared__ float As[16][68];
  __shared__ float Bs[16][68];
  int b = blockIdx.z;
  int d0 = blockIdx.x * 64;
  int n0 = blockIdx.y * 64;
  int tid = threadIdx.x;
  int tx = tid & 15, ty = tid >> 4;
  const float* Zb = ZF + (size_t)b * CT * N_;
  float acc[4][4] = {};
  for (int k0 = 0; k0 < CT; k0 += 16) {
#pragma unroll
    for (int i = 0; i < 4; ++i) {
      int kl = (tid >> 6) + 4 * i;
      int k = k0 + kl;
      int d = d0 + (tid & 63);
      As[kl][tid & 63] = (k < CT && d < Dout) ? W[k * Dout + d] : 0.f;
      Bs[kl][tid & 63] = (k < CT) ? Zb[k * N_ + n0 + (tid & 63)] : 0.f;
    }
    __syncthreads();
#pragma unroll
    for (int kk = 0; kk < 16; ++kk) {
      float a[4], bb[4];
#pragma unroll
      for (int i = 0; i < 4; ++i) a[i] = As[kk][ty * 4 + i];
#pragma unroll
      for (int i = 0; i < 4; ++i) bb[i] = Bs[kk][tx * 4 + i];
#pragma unroll
      for (int i = 0; i < 4; ++i)
#pragma unroll
        for (int jj = 0; jj < 4; ++jj)
          acc[i][jj] = fmaf(a[i], bb[jj], acc[i][jj]);
    }
    __syncthreads();
  }
#pragma unroll
  for (int i = 0; i < 4; ++i) {
    int d = d0 + ty * 4 + i;
    if (d >= Dout) continue;
    float bv = bias[d];
#pragma unroll
    for (int jj = 0; jj < 4; ++jj) {
      int n = n0 + tx * 4 + jj;
      float v = acc[i][jj] + bv;
      v = (act == 0) ? (1.f / (1.f + expf(-v))) : tanhf(v);
      Out[((size_t)(b * Dout + d)) * N_ + n] = v;
    }
  }
}

// h = u*h + (1-u)*c ; u = RU channels [64,128), c = CC (tanh already applied)
__global__ __launch_bounds__(256) void update_h_k(float* __restrict__ h,
                                                  const float* __restrict__ RU,
                                                  const float* __restrict__ CC) {
  int idx = blockIdx.x * blockDim.x + threadIdx.x;
  if (idx >= B_ * H_ * N_) return;
  int n = idx & 511;
  int j = (idx >> 9) & 63;
  int b = idx >> 15;
  float u = RU[(b * 128 + 64 + j) * N_ + n];
  float c = CC[(b * H_ + j) * N_ + n];
  float hv = h[idx];
  h[idx] = u * hv + (1.f - u) * c;
}

// y[b,n] = proj_b + sum_j proj_w[j] * h1[b,j,n]; write ybuf and strided output
__global__ __launch_bounds__(256) void proj_out_k(const float* __restrict__ h1,
                                                  const float* __restrict__ pw,
                                                  const float* __restrict__ pb,
                                                  float* __restrict__ ybuf,
                                                  float* __restrict__ out, int k) {
  int idx = blockIdx.x * blockDim.x + threadIdx.x;
  if (idx >= B_ * N_) return;
  int n = idx & 511;
  int b = idx >> 9;
  float s = pb[0];
#pragma unroll
  for (int j = 0; j < H_; ++j)
    s = fmaf(pw[j], h1[(b * H_ + j) * N_ + n], s);
  ybuf[idx] = s;
  out[(size_t)idx * 12 + k] = s;
}

extern "C" void kernel_launch(void* const* d_in, const int* in_sizes, int n_in,
                              void* d_out, int out_size, void* d_ws, size_t ws_size,
                              hipStream_t stream) {
  const float* inputs   = (const float*)d_in[0];
  const float* supports = (const float*)d_in[1];
  const float* e0_wg = (const float*)d_in[2];
  const float* e0_bg = (const float*)d_in[3];
  const float* e0_wc = (const float*)d_in[4];
  const float* e0_bc = (const float*)d_in[5];
  const float* e1_wg = (const float*)d_in[6];
  const float* e1_bg = (const float*)d_in[7];
  const float* e1_wc = (const float*)d_in[8];
  const float* e1_bc = (const float*)d_in[9];
  const float* d0_wg = (const float*)d_in[10];
  const float* d0_bg = (const float*)d_in[11];
  const float* d0_wc = (const float*)d_in[12];
  const float* d0_bc = (const float*)d_in[13];
  const float* d1_wg = (const float*)d_in[14];
  const float* d1_bg = (const float*)d_in[15];
  const float* d1_wc = (const float*)d_in[16];
  const float* d1_bc = (const float*)d_in[17];
  const float* proj_w = (const float*)d_in[18];
  const float* proj_b = (const float*)d_in[19];
  float* out = (float*)d_out;

  char* p = (char*)d_ws;
  float* Bmat = (float*)p; p += (size_t)512 * 2048 * 4;           // 4 MB
  float* h0   = (float*)p; p += (size_t)B_ * H_ * N_ * 4;         // 8 MB
  float* h1   = (float*)p; p += (size_t)B_ * H_ * N_ * 4;         // 8 MB
  float* RU   = (float*)p; p += (size_t)B_ * 128 * N_ * 4;        // 16 MB
  float* CC   = (float*)p; p += (size_t)B_ * H_ * N_ * 4;         // 8 MB
  float* ybuf = (float*)p; p += (size_t)B_ * N_ * 4;              // 128 KB
  float* ZF   = (float*)p; p += (size_t)B_ * 640 * N_ * 4;        // 80 MB

  hipMemsetAsync(h0, 0, (size_t)B_ * H_ * N_ * 4, stream);
  hipMemsetAsync(h1, 0, (size_t)B_ * H_ * N_ * 4, stream);
  hipMemsetAsync(ybuf, 0, (size_t)B_ * N_ * 4, stream);

  bmat_copy_k<<<(2 * N_ * N_ + 255) / 256, 256, 0, stream>>>(supports, Bmat);
  bmat_sq_k<<<dim3(32, 32, 2), dim3(16, 16), 0, stream>>>(supports, Bmat);

  auto cell = [&](int Cx, const float* x, int xmode, int t, float* h,
                  const float* wg, const float* bg, const float* wc, const float* bc) {
    int C = Cx + H_;
    int CT = 5 * C;
    int total = B_ * C * N_;
    int cblk = (C + 63) / 64;
    // gate gconv: z = [x, h]
    pack_z_k<<<(total + 255) / 256, 256, 0, stream>>>(ZF, CT, Cx, x, xmode, t, h, nullptr);
    gemm_diff_k<<<dim3(cblk, 32, B_), 256, 0, stream>>>(Bmat, ZF, C, CT);
    gemm_proj_k<<<dim3(2, 8, B_), 256, 0, stream>>>(wg, bg, ZF, RU, CT, 128, 0);
    // candidate gconv: z = [x, r*h]
    pack_z_k<<<(total + 255) / 256, 256, 0, stream>>>(ZF, CT, Cx, x, xmode, t, h, RU);
    gemm_diff_k<<<dim3(cblk, 32, B_), 256, 0, stream>>>(Bmat, ZF, C, CT);
    gemm_proj_k<<<dim3(1, 8, B_), 256, 0, stream>>>(wc, bc, ZF, CC, CT, 64, 1);
    update_h_k<<<(B_ * H_ * N_ + 255) / 256, 256, 0, stream>>>(h, RU, CC);
  };

  for (int t = 0; t < 12; ++t) {
    cell(2, inputs, 0, t, h0, e0_wg, e0_bg, e0_wc, e0_bc);
    cell(64, h0, 1, 0, h1, e1_wg, e1_bg, e1_wc, e1_bc);
  }
  for (int k = 0; k < 12; ++k) {
    cell(1, ybuf, 1, 0, h0, d0_wg, d0_bg, d0_wc, d0_bc);
    cell(64, h0, 1, 0, h1, d1_wg, d1_bg, d1_wc, d1_bc);
    proj_out_k<<<(B_ * N_ + 255) / 256, 256, 0, stream>>>(h1, proj_w, proj_b, ybuf, out, k);
  }
}

// Round 2
// 18011.830 us; speedup vs baseline: 1.7353x; 1.7353x over previous
//
#include <hip/hip_runtime.h>

#define B_ 64
#define N_ 512
#define H_ 64

typedef __attribute__((ext_vector_type(8))) short bf8_t;   // 8 bf16 in 4 VGPRs
typedef __attribute__((ext_vector_type(4))) float f4_t;    // MFMA accumulator

#define MFMA(a, b, c) __builtin_amdgcn_mfma_f32_16x16x32_bf16(a, b, c, 0, 0, 0)

__device__ __forceinline__ ushort f2bf(float x) {
  union { float f; unsigned u; } v; v.f = x;
  unsigned r = v.u + 0x7FFFu + ((v.u >> 16) & 1u);   // RNE
  return (ushort)(r >> 16);
}
__device__ __forceinline__ float bf2f(ushort h) {
  union { unsigned u; float f; } v; v.u = ((unsigned)h) << 16;
  return v.f;
}

// ---------------------------------------------------------------------------
// Prep: SS[s] = S[s]^2 (f32), 16x16 tiles
// ---------------------------------------------------------------------------
__global__ __launch_bounds__(256) void ssq_k(const float* __restrict__ S,
                                             float* __restrict__ SS) {
  int s = blockIdx.z;
  const float* Ss = S + s * N_ * N_;
  __shared__ float Ta[16][17], Tb[16][17];
  int n = blockIdx.y * 16 + threadIdx.y;
  int m = blockIdx.x * 16 + threadIdx.x;
  float acc = 0.f;
  for (int p0 = 0; p0 < N_; p0 += 16) {
    Ta[threadIdx.y][threadIdx.x] = Ss[n * N_ + p0 + threadIdx.x];
    Tb[threadIdx.y][threadIdx.x] = Ss[(p0 + threadIdx.y) * N_ + m];
    __syncthreads();
#pragma unroll
    for (int pp = 0; pp < 16; ++pp)
      acc = fmaf(Ta[threadIdx.y][pp], Tb[pp][threadIdx.x], acc);
    __syncthreads();
  }
  SS[((size_t)s * N_ + n) * N_ + m] = acc;
}

// BmT rows (t*512+n), k-contig over m: [S0, S0^2, S1, S1^2], split hi/lo bf16
__global__ __launch_bounds__(256) void bmt_k(const float* __restrict__ S,
                                             const float* __restrict__ SS,
                                             ushort* __restrict__ Bh,
                                             ushort* __restrict__ Bl) {
  int idx = blockIdx.x * 256 + threadIdx.x;
  if (idx >= 4 * N_ * N_) return;
  int m = idx & 511;
  int n = (idx >> 9) & 511;
  int t = idx >> 18;
  float v;
  if (t == 0)      v = S[(size_t)n * N_ + m];
  else if (t == 1) v = SS[(size_t)n * N_ + m];
  else if (t == 2) v = S[((size_t)N_ + n) * N_ + m];
  else             v = SS[((size_t)N_ + n) * N_ + m];
  ushort hh = f2bf(v), ll = f2bf(v - bf2f(hh));
  Bh[idx] = hh; Bl[idx] = ll;
}

// W (CT x Dout) -> Wt hi/lo (Dout x Kpad), zero-padded rows k >= CT
__global__ __launch_bounds__(256) void wprep_k(const float* __restrict__ W,
                                               ushort* __restrict__ Wh,
                                               ushort* __restrict__ Wl,
                                               int CT, int Kpad, int Dout) {
  int idx = blockIdx.x * 256 + threadIdx.x;
  if (idx >= Dout * Kpad) return;
  int k = idx % Kpad, d = idx / Kpad;
  float v = (k < CT) ? W[(size_t)k * Dout + d] : 0.f;
  ushort hh = f2bf(v), ll = f2bf(v - bf2f(hh));
  Wh[idx] = hh; Wl[idx] = ll;
}

// ---------------------------------------------------------------------------
// Pack z = [x, h]: writes Zc hi/lo (c-major, lda=512) and ZFT t=0 block
// (n-major, row stride 640) via an LDS transpose. grid(ceil(C/64), 8, B)
// ---------------------------------------------------------------------------
__global__ __launch_bounds__(256) void pack_k(const float* __restrict__ xsrc, int xmode,
                                              int t, int Cx, int C,
                                              const float* __restrict__ hcell,
                                              ushort* __restrict__ Zch, ushort* __restrict__ Zcl,
                                              ushort* __restrict__ Fh, ushort* __restrict__ Fl) {
  __shared__ float tile[64][65];
  int b = blockIdx.z;
  int c0 = blockIdx.x * 64, n0 = blockIdx.y * 64;
  int tl = threadIdx.x & 63, tw = threadIdx.x >> 6;
#pragma unroll
  for (int p = 0; p < 16; ++p) {
    int cl = tw + 4 * p, c = c0 + cl, n = n0 + tl;
    if (c < C) {
      float v;
      if (c < Cx) v = (xmode == 0) ? xsrc[((size_t)(b * Cx + c) * N_ + n) * 12 + t]
                                   : xsrc[(size_t)(b * Cx + c) * N_ + n];
      else        v = hcell[((size_t)(b << 6) + (c - Cx)) * N_ + n];
      ushort hh = f2bf(v), ll = f2bf(v - bf2f(hh));
      size_t zi = ((size_t)b * C + c) * N_ + n;
      Zch[zi] = hh; Zcl[zi] = ll;
      tile[cl][tl] = v;
    }
  }
  __syncthreads();
#pragma unroll
  for (int p = 0; p < 16; ++p) {
    int nl = tw + 4 * p, n = n0 + nl, c = c0 + tl;
    if (c < C) {
      float v = tile[tl][nl];
      ushort hh = f2bf(v), ll = f2bf(v - bf2f(hh));
      size_t fi = ((size_t)(b * N_ + n)) * 640 + c;
      Fh[fi] = hh; Fl[fi] = ll;
    }
  }
}

// ---------------------------------------------------------------------------
// Split-bf16 MFMA core: C[m][n] = sum_k A[m][k]*B[n][k]  (both K-contiguous)
// 3-term: Ah*Bh + Ah*Bl + Al*Bh. Wave tile 64x64, 4x4 frags of 16x16x32.
// ---------------------------------------------------------------------------
__device__ __forceinline__ void gemm_core(
    const ushort* __restrict__ Ah, const ushort* __restrict__ Al, int lda, int M,
    const ushort* __restrict__ Bh, const ushort* __restrict__ Bl, int ldb,
    int K, int m0, int n0, int lr, int kq, f4_t acc[4][4]) {
  const ushort* pA[8]; const ushort* pB[8];
#pragma unroll
  for (int i = 0; i < 4; ++i) {
    int r = m0 + 16 * i + lr; if (r >= M) r = 0;   // clamp; garbage rows not stored
    size_t off = (size_t)r * lda + kq * 8;
    pA[i] = Ah + off; pA[i + 4] = Al + off;
  }
#pragma unroll
  for (int j = 0; j < 4; ++j) {
    size_t off = (size_t)(n0 + 16 * j + lr) * ldb + kq * 8;
    pB[j] = Bh + off; pB[j + 4] = Bl + off;
  }
  for (int k = 0; k < K; k += 32) {
    bf8_t ah[4], al[4], bh[4], bl[4];
#pragma unroll
    for (int i = 0; i < 4; ++i) {
      ah[i] = *(const bf8_t*)(pA[i] + k);
      al[i] = *(const bf8_t*)(pA[i + 4] + k);
    }
#pragma unroll
    for (int j = 0; j < 4; ++j) {
      bh[j] = *(const bf8_t*)(pB[j] + k);
      bl[j] = *(const bf8_t*)(pB[j + 4] + k);
    }
#pragma unroll
    for (int i = 0; i < 4; ++i)
#pragma unroll
      for (int j = 0; j < 4; ++j) {
        acc[i][j] = MFMA(ah[i], bh[j], acc[i][j]);
        acc[i][j] = MFMA(ah[i], bl[j], acc[i][j]);
        acc[i][j] = MFMA(al[i], bh[j], acc[i][j]);
      }
  }
}

// ---------------------------------------------------------------------------
// Diffusion GEMM: A (M x 512) @ BmT^T -> feats, written into ZFT hi/lo at
// f = (1+t)*C + cbase + c, col jg -> (t = jg>>9, n = jg&511).
// ---------------------------------------------------------------------------
template <int WMv, int WNv>
__global__ __launch_bounds__(256) void diff_k(
    const ushort* __restrict__ Ah, const ushort* __restrict__ Al, int M, int strideA,
    const ushort* __restrict__ Bh, const ushort* __restrict__ Bl,
    ushort* Fh, ushort* Fl, int C, int cbase) {
  int tid = threadIdx.x, lane = tid & 63, wave = tid >> 6;
  int lr = lane & 15, kq = lane >> 4;
  int b = blockIdx.z;
  int m0 = (wave / WNv) * 64;
  int n0 = blockIdx.x * (WNv * 64) + (wave % WNv) * 64;
  f4_t acc[4][4] = {};
  gemm_core(Ah + (size_t)b * strideA, Al + (size_t)b * strideA, 512, M,
            Bh, Bl, 512, 512, m0, n0, lr, kq, acc);
#pragma unroll
  for (int i = 0; i < 4; ++i) {
    int c = m0 + 16 * i + kq * 4;
    if (c >= M) continue;
#pragma unroll
    for (int j = 0; j < 4; ++j) {
      int jg = n0 + 16 * j + lr;
      int t = jg >> 9, n = jg & 511;
      size_t base = ((size_t)(b * N_ + n)) * 640 + (size_t)(1 + t) * C + cbase + c;
      f4_t v = acc[i][j];
      ushort hh[4], ll[4];
#pragma unroll
      for (int r = 0; r < 4; ++r) { hh[r] = f2bf(v[r]); ll[r] = f2bf(v[r] - bf2f(hh[r])); }
      if ((c + 3 < M) && !(base & 1)) {
        *(unsigned*)(Fh + base)     = (unsigned)hh[0] | ((unsigned)hh[1] << 16);
        *(unsigned*)(Fh + base + 2) = (unsigned)hh[2] | ((unsigned)hh[3] << 16);
        *(unsigned*)(Fl + base)     = (unsigned)ll[0] | ((unsigned)ll[1] << 16);
        *(unsigned*)(Fl + base + 2) = (unsigned)ll[2] | ((unsigned)ll[3] << 16);
      } else {
#pragma unroll
        for (int r = 0; r < 4; ++r)
          if (c + r < M) { Fh[base + r] = hh[r]; Fl[base + r] = ll[r]; }
      }
    }
  }
}

// ---------------------------------------------------------------------------
// Gate projection (Dout=128): sigmoid; d<64 -> rh into Zc + ZFT t0 h-block;
// d>=64 -> U. A = Wt (128 x Kpad), B = ZFT rows (n, stride 640).
// ---------------------------------------------------------------------------
__global__ __launch_bounds__(256) void projg_k(
    const ushort* __restrict__ Wh, const ushort* __restrict__ Wl, int Kpad,
    const ushort* Fh, const ushort* Fl,
    const float* __restrict__ bg, const float* __restrict__ hcell,
    float* __restrict__ U, ushort* __restrict__ Zch, ushort* __restrict__ Zcl,
    int C, int Cx) {
  int tid = threadIdx.x, lane = tid & 63, wave = tid >> 6;
  int lr = lane & 15, kq = lane >> 4;
  int b = blockIdx.z;
  int m0 = (wave >> 1) * 64;
  int n0 = blockIdx.x * 128 + (wave & 1) * 64;
  const ushort* Fb_h = Fh + (size_t)b * N_ * 640;
  const ushort* Fb_l = Fl + (size_t)b * N_ * 640;
  f4_t acc[4][4] = {};
  gemm_core(Wh, Wl, Kpad, 128, Fb_h, Fb_l, 640, Kpad, m0, n0, lr, kq, acc);
#pragma unroll
  for (int i = 0; i < 4; ++i) {
    int d = m0 + 16 * i + kq * 4;
#pragma unroll
    for (int j = 0; j < 4; ++j) {
      int n = n0 + 16 * j + lr;
      f4_t v = acc[i][j];
#pragma unroll
      for (int r = 0; r < 4; ++r) {
        int dd = d + r;
        float s = 1.f / (1.f + expf(-(v[r] + bg[dd])));
        if (dd < 64) {
          float rh = s * hcell[((size_t)(b << 6) + dd) * N_ + n];
          ushort hh = f2bf(rh), ll = f2bf(rh - bf2f(hh));
          size_t zi = ((size_t)b * C + Cx + dd) * N_ + n;
          Zch[zi] = hh; Zcl[zi] = ll;
          size_t fi = ((size_t)(b * N_ + n)) * 640 + Cx + dd;
          ((ushort*)Fh)[fi] = hh; ((ushort*)Fl)[fi] = ll;
        } else {
          U[((size_t)(b << 6) + (dd - 64)) * N_ + n] = s;
        }
      }
    }
  }
}

// ---------------------------------------------------------------------------
// Candidate projection (Dout=64) + fused GRU update: h = u*h + (1-u)*tanh(.)
// Config 1x4 (tile 64 x 256).
// ---------------------------------------------------------------------------
__global__ __launch_bounds__(256) void projc_k(
    const ushort* __restrict__ Wh, const ushort* __restrict__ Wl, int Kpad,
    const ushort* __restrict__ Fh, const ushort* __restrict__ Fl,
    const float* __restrict__ bc, const float* __restrict__ U,
    float* __restrict__ hcell) {
  int tid = threadIdx.x, lane = tid & 63, wave = tid >> 6;
  int lr = lane & 15, kq = lane >> 4;
  int b = blockIdx.z;
  int n0 = blockIdx.x * 256 + wave * 64;
  const ushort* Fb_h = Fh + (size_t)b * N_ * 640;
  const ushort* Fb_l = Fl + (size_t)b * N_ * 640;
  f4_t acc[4][4] = {};
  gemm_core(Wh, Wl, Kpad, 64, Fb_h, Fb_l, 640, Kpad, 0, n0, lr, kq, acc);
#pragma unroll
  for (int i = 0; i < 4; ++i) {
    int d = 16 * i + kq * 4;
#pragma unroll
    for (int j = 0; j < 4; ++j) {
      int n = n0 + 16 * j + lr;
      f4_t v = acc[i][j];
#pragma unroll
      for (int r = 0; r < 4; ++r) {
        int dd = d + r;
        float ct = tanhf(v[r] + bc[dd]);
        size_t ix = ((size_t)(b << 6) + dd) * N_ + n;
        float u = U[ix];
        hcell[ix] = u * hcell[ix] + (1.f - u) * ct;
      }
    }
  }
}

// y[b,n] = proj_b + sum_j proj_w[j] * h1[b,j,n]; write ybuf and strided output
__global__ __launch_bounds__(256) void proj_out_k(const float* __restrict__ h1,
                                                  const float* __restrict__ pw,
                                                  const float* __restrict__ pb,
                                                  float* __restrict__ ybuf,
                                                  float* __restrict__ out, int k) {
  int idx = blockIdx.x * blockDim.x + threadIdx.x;
  if (idx >= B_ * N_) return;
  int n = idx & 511;
  int b = idx >> 9;
  float s = pb[0];
#pragma unroll
  for (int j = 0; j < H_; ++j)
    s = fmaf(pw[j], h1[((size_t)(b * H_) + j) * N_ + n], s);
  ybuf[idx] = s;
  out[(size_t)idx * 12 + k] = s;
}

extern "C" void kernel_launch(void* const* d_in, const int* in_sizes, int n_in,
                              void* d_out, int out_size, void* d_ws, size_t ws_size,
                              hipStream_t stream) {
  const float* inputs   = (const float*)d_in[0];
  const float* supports = (const float*)d_in[1];
  const float* Wg[4] = { (const float*)d_in[2],  (const float*)d_in[6],
                         (const float*)d_in[10], (const float*)d_in[14] };
  const float* Bg[4] = { (const float*)d_in[3],  (const float*)d_in[7],
                         (const float*)d_in[11], (const float*)d_in[15] };
  const float* Wc[4] = { (const float*)d_in[4],  (const float*)d_in[8],
                         (const float*)d_in[12], (const float*)d_in[16] };
  const float* Bc[4] = { (const float*)d_in[5],  (const float*)d_in[9],
                         (const float*)d_in[13], (const float*)d_in[17] };
  const float* proj_w = (const float*)d_in[18];
  const float* proj_b = (const float*)d_in[19];
  float* out = (float*)d_out;

  char* p = (char*)d_ws;
  auto carve = [&](size_t bytes) { void* q = p; p += (bytes + 255) & ~(size_t)255; return q; };
  ushort* BmThi = (ushort*)carve((size_t)4 * N_ * N_ * 2);
  ushort* BmTlo = (ushort*)carve((size_t)4 * N_ * N_ * 2);
  ushort* Zchi  = (ushort*)carve((size_t)B_ * 128 * N_ * 2);
  ushort* Zclo  = (ushort*)carve((size_t)B_ * 128 * N_ * 2);
  ushort* ZFThi = (ushort*)carve((size_t)B_ * N_ * 640 * 2);
  ushort* ZFTlo = (ushort*)carve((size_t)B_ * N_ * 640 * 2);
  float*  U     = (float*)carve((size_t)B_ * H_ * N_ * 4);
  float*  h0    = (float*)carve((size_t)B_ * H_ * N_ * 4);
  float*  h1    = (float*)carve((size_t)B_ * H_ * N_ * 4);
  float*  ybuf  = (float*)carve((size_t)B_ * N_ * 4);
  // Wt splits: cells order e0,e1,d0,d1; per cell gate(128 x Kpad), cand(64 x Kpad)
  const int CTs[4]   = { 330, 640, 325, 640 };
  const int Kpads[4] = { 352, 640, 352, 640 };
  ushort* Wth[8]; ushort* Wtl[8];
  for (int c = 0; c < 4; ++c) {
    Wth[2 * c]     = (ushort*)carve((size_t)128 * Kpads[c] * 2);
    Wtl[2 * c]     = (ushort*)carve((size_t)128 * Kpads[c] * 2);
    Wth[2 * c + 1] = (ushort*)carve((size_t)64 * Kpads[c] * 2);
    Wtl[2 * c + 1] = (ushort*)carve((size_t)64 * Kpads[c] * 2);
  }
  float* SSbuf = (float*)U;   // overlay: SS only needed during prep

  hipMemsetAsync(h0, 0, (size_t)B_ * H_ * N_ * 4, stream);
  hipMemsetAsync(h1, 0, (size_t)B_ * H_ * N_ * 4, stream);
  hipMemsetAsync(ybuf, 0, (size_t)B_ * N_ * 4, stream);

  ssq_k<<<dim3(32, 32, 2), dim3(16, 16), 0, stream>>>(supports, SSbuf);
  bmt_k<<<(4 * N_ * N_ + 255) / 256, 256, 0, stream>>>(supports, SSbuf, BmThi, BmTlo);
  for (int c = 0; c < 4; ++c) {
    wprep_k<<<(128 * Kpads[c] + 255) / 256, 256, 0, stream>>>(Wg[c], Wth[2 * c], Wtl[2 * c],
                                                              CTs[c], Kpads[c], 128);
    wprep_k<<<(64 * Kpads[c] + 255) / 256, 256, 0, stream>>>(Wc[c], Wth[2 * c + 1], Wtl[2 * c + 1],
                                                             CTs[c], Kpads[c], 64);
  }

  auto cell = [&](int ci, int Cx, const float* x, int xmode, int t, float* h) {
    int C = Cx + H_;
    int Kpad = Kpads[ci];
    pack_k<<<dim3((C + 63) / 64, 8, B_), 256, 0, stream>>>(x, xmode, t, Cx, C, h,
                                                           Zchi, Zclo, ZFThi, ZFTlo);
    diff_k<2, 2><<<dim3(16, 1, B_), 256, 0, stream>>>(Zchi, Zclo, C, C * N_,
                                                      BmThi, BmTlo, ZFThi, ZFTlo, C, 0);
    projg_k<<<dim3(4, 1, B_), 256, 0, stream>>>(Wth[2 * ci], Wtl[2 * ci], Kpad,
                                                ZFThi, ZFTlo, Bg[ci], h, U, Zchi, Zclo, C, Cx);
    diff_k<1, 4><<<dim3(8, 1, B_), 256, 0, stream>>>(Zchi + (size_t)Cx * N_, Zclo + (size_t)Cx * N_,
                                                     64, C * N_, BmThi, BmTlo,
                                                     ZFThi, ZFTlo, C, Cx);
    projc_k<<<dim3(2, 1, B_), 256, 0, stream>>>(Wth[2 * ci + 1], Wtl[2 * ci + 1], Kpad,
                                                ZFThi, ZFTlo, Bc[ci], U, h);
  };

  for (int t = 0; t < 12; ++t) {
    cell(0, 2, inputs, 0, t, h0);
    cell(1, 64, h0, 1, 0, h1);
  }
  for (int k = 0; k < 12; ++k) {
    cell(2, 1, ybuf, 1, 0, h0);
    cell(3, 64, h0, 1, 0, h1);
    proj_out_k<<<(B_ * N_ + 255) / 256, 256, 0, stream>>>(h1, proj_w, proj_b, ybuf, out, k);
  }
}

// Round 3
// 15762.355 us; speedup vs baseline: 1.9829x; 1.1427x over previous
//
#include <hip/hip_runtime.h>

#define B_ 64
#define N_ 512

typedef __attribute__((ext_vector_type(8))) short bf8_t;   // 8 bf16 (4 VGPRs)
typedef __attribute__((ext_vector_type(4))) float f4_t;    // MFMA accumulator

#define MFMA(a, b, c) __builtin_amdgcn_mfma_f32_16x16x32_bf16(a, b, c, 0, 0, 0)

__device__ __forceinline__ ushort f2bf(float x) {
  union { float f; unsigned u; } v; v.f = x;
  unsigned r = v.u + 0x7FFFu + ((v.u >> 16) & 1u);   // RNE
  return (ushort)(r >> 16);
}
__device__ __forceinline__ float bf2f(ushort h) {
  union { unsigned u; float f; } v; v.u = ((unsigned)h) << 16;
  return v.f;
}

// async global->LDS, 16B per lane. LDS dest must be linear (base + lane*16).
__device__ __forceinline__ void gld16(const ushort* g, ushort* l) {
  __builtin_amdgcn_global_load_lds(
      (const __attribute__((address_space(1))) unsigned int*)(uintptr_t)g,
      (__attribute__((address_space(3))) unsigned int*)(uintptr_t)l,
      16, 0, 0);
}

// ---------------------------------------------------------------------------
// Split-bf16 LDS-staged GEMM core. A (BM x K), B (BN x K), both K-contiguous.
// Tiles Ah|Al|Bh|Bl staged per BK=32 chunk via global_load_lds, double-buffered.
// Wave tile 64x64 (4x4 frags), 3-term MFMA. Waves: WM x WN.
// ---------------------------------------------------------------------------
template <int BM, int BN, int WM, int WN>
__device__ __forceinline__ void core(
    const ushort* Ah, const ushort* Al, int lda,
    const ushort* Bh, const ushort* Bl, int ldb,
    int K, ushort* lds, f4_t acc[4][4]) {
  constexpr int SA = BM / 16, SB = BN / 16;        // 1KB segments per half-tile
  constexpr int NSEG = 2 * SA + 2 * SB;
  constexpr int NW = WM * WN;
  constexpr int SSZ = (2 * BM + 2 * BN) * 32;      // ushorts per stage
  constexpr int AH_O = 0, AL_O = BM * 32, BH_O = 2 * BM * 32, BL_O = 2 * BM * 32 + BN * 32;
  const int lane = threadIdx.x & 63, wave = threadIdx.x >> 6;
  const int lr = lane & 15, kq = lane >> 4;
  const int wm = wave / WN, wn = wave % WN;
  const int rseg = lane >> 2, coff = (lane & 3) * 8;

  auto stage = [&](int buf, int k0) {
    ushort* lb = lds + buf * SSZ;
    for (int s = wave; s < NSEG; s += NW) {
      const ushort* gb; int ld, toff, si;
      if (s < SA)               { si = s;               gb = Ah; ld = lda; toff = AH_O; }
      else if (s < 2 * SA)      { si = s - SA;          gb = Al; ld = lda; toff = AL_O; }
      else if (s < 2 * SA + SB) { si = s - 2 * SA;      gb = Bh; ld = ldb; toff = BH_O; }
      else                      { si = s - 2 * SA - SB; gb = Bl; ld = ldb; toff = BL_O; }
      const ushort* g = gb + (size_t)(si * 16 + rseg) * ld + k0 + coff;
      gld16(g, lb + toff + si * 512 + lane * 8);
    }
  };

  const int nc = K >> 5;
  stage(0, 0);
  int buf = 0;
  for (int c = 0; c < nc; ++c) {
    __syncthreads();                       // staged chunk c ready; prior reads done
    if (c + 1 < nc) stage(buf ^ 1, (c + 1) << 5);
    const ushort* lb = lds + buf * SSZ;
    bf8_t ah[4], al[4], bh[4], bl[4];
#pragma unroll
    for (int i = 0; i < 4; ++i) {
      int r = wm * 64 + 16 * i + lr;
      ah[i] = *(const bf8_t*)(lb + AH_O + r * 32 + kq * 8);
      al[i] = *(const bf8_t*)(lb + AL_O + r * 32 + kq * 8);
    }
#pragma unroll
    for (int j = 0; j < 4; ++j) {
      int r = wn * 64 + 16 * j + lr;
      bh[j] = *(const bf8_t*)(lb + BH_O + r * 32 + kq * 8);
      bl[j] = *(const bf8_t*)(lb + BL_O + r * 32 + kq * 8);
    }
#pragma unroll
    for (int i = 0; i < 4; ++i)
#pragma unroll
      for (int j = 0; j < 4; ++j) {
        acc[i][j] = MFMA(ah[i], bh[j], acc[i][j]);
        acc[i][j] = MFMA(ah[i], bl[j], acc[i][j]);
        acc[i][j] = MFMA(al[i], bh[j], acc[i][j]);
      }
    buf ^= 1;
  }
}

// ---------------------------------------------------------------------------
// Prep kernels
// ---------------------------------------------------------------------------
__global__ __launch_bounds__(256) void ssq_k(const float* __restrict__ S,
                                             float* __restrict__ SS) {
  int s = blockIdx.z;
  const float* Ss = S + s * N_ * N_;
  __shared__ float Ta[16][17], Tb[16][17];
  int n = blockIdx.y * 16 + threadIdx.y;
  int m = blockIdx.x * 16 + threadIdx.x;
  float acc = 0.f;
  for (int p0 = 0; p0 < N_; p0 += 16) {
    Ta[threadIdx.y][threadIdx.x] = Ss[n * N_ + p0 + threadIdx.x];
    Tb[threadIdx.y][threadIdx.x] = Ss[(p0 + threadIdx.y) * N_ + m];
    __syncthreads();
#pragma unroll
    for (int pp = 0; pp < 16; ++pp)
      acc = fmaf(Ta[threadIdx.y][pp], Tb[pp][threadIdx.x], acc);
    __syncthreads();
  }
  SS[((size_t)s * N_ + n) * N_ + m] = acc;
}

__global__ __launch_bounds__(256) void bmt_k(const float* __restrict__ S,
                                             const float* __restrict__ SS,
                                             ushort* __restrict__ Bh,
                                             ushort* __restrict__ Bl) {
  int idx = blockIdx.x * 256 + threadIdx.x;
  if (idx >= 4 * N_ * N_) return;
  int m = idx & 511;
  int n = (idx >> 9) & 511;
  int t = idx >> 18;
  float v;
  if (t == 0)      v = S[(size_t)n * N_ + m];
  else if (t == 1) v = SS[(size_t)n * N_ + m];
  else if (t == 2) v = S[((size_t)N_ + n) * N_ + m];
  else             v = SS[((size_t)N_ + n) * N_ + m];
  ushort hh = f2bf(v), ll = f2bf(v - bf2f(hh));
  Bh[idx] = hh; Bl[idx] = ll;
}

__global__ __launch_bounds__(256) void wprep_k(const float* __restrict__ W,
                                               ushort* __restrict__ Wh,
                                               ushort* __restrict__ Wl,
                                               int CT, int Kpad, int Dout) {
  int idx = blockIdx.x * 256 + threadIdx.x;
  if (idx >= Dout * Kpad) return;
  int k = idx % Kpad, d = idx / Kpad;
  float v = (k < CT) ? W[(size_t)k * Dout + d] : 0.f;
  ushort hh = f2bf(v), ll = f2bf(v - bf2f(hh));
  Wh[idx] = hh; Wl[idx] = ll;
}

// ---------------------------------------------------------------------------
// Pack z = [x, h]: Zc hi/lo (row (b*128+c), ld 512) + ZFT t=0 block (row n-flat,
// ld 640) via LDS transpose. grid(ceil(C/64), 8, B)
// ---------------------------------------------------------------------------
__global__ __launch_bounds__(256) void pack_k(const float* __restrict__ xsrc, int xmode,
                                              int t, int Cx, int C,
                                              const float* __restrict__ hcell,
                                              ushort* __restrict__ Zch, ushort* __restrict__ Zcl,
                                              ushort* __restrict__ Fh, ushort* __restrict__ Fl) {
  __shared__ float tile[64][65];
  int b = blockIdx.z;
  int c0 = blockIdx.x * 64, n0 = blockIdx.y * 64;
  int tl = threadIdx.x & 63, tw = threadIdx.x >> 6;
#pragma unroll
  for (int p = 0; p < 16; ++p) {
    int cl = tw + 4 * p, c = c0 + cl, n = n0 + tl;
    if (c < C) {
      float v;
      if (c < Cx) v = (xmode == 0) ? xsrc[((size_t)(b * Cx + c) * N_ + n) * 12 + t]
                                   : xsrc[(size_t)(b * Cx + c) * N_ + n];
      else        v = hcell[((size_t)(b << 6) + (c - Cx)) * N_ + n];
      ushort hh = f2bf(v), ll = f2bf(v - bf2f(hh));
      size_t zi = ((size_t)(b * 128) + c) * N_ + n;
      Zch[zi] = hh; Zcl[zi] = ll;
      tile[cl][tl] = v;
    }
  }
  __syncthreads();
#pragma unroll
  for (int p = 0; p < 16; ++p) {
    int nl = tw + 4 * p, n = n0 + nl, c = c0 + tl;
    if (c < C) {
      float v = tile[tl][nl];
      ushort hh = f2bf(v), ll = f2bf(v - bf2f(hh));
      size_t fi = ((size_t)(b * N_ + n)) * 640 + c;
      Fh[fi] = hh; Fl[fi] = ll;
    }
  }
}

// ---------------------------------------------------------------------------
// Diffusion GEMM: A = Zc slab rows (per b), B = BmT (2048 x 512).
// Out[c, jg] -> ZFT[b*512 + (jg&511)][(1+(jg>>9))*C + cbase + c], c < climit.
// ---------------------------------------------------------------------------
template <int WM, int WN>
__global__ __launch_bounds__(WM * WN * 64) void diffg_k(
    const ushort* Ah, const ushort* Al,
    const ushort* Bh, const ushort* Bl,
    ushort* Fh, ushort* Fl, int C, int cbase, int climit) {
  constexpr int BM = WM * 64, BN = WN * 64;
  __shared__ __attribute__((aligned(16))) ushort lds[2 * (2 * BM + 2 * BN) * 32];
  int b = blockIdx.z;
  int n0 = blockIdx.x * BN;
  f4_t acc[4][4] = {};
  core<BM, BN, WM, WN>(Ah + (size_t)b * 128 * 512, Al + (size_t)b * 128 * 512, 512,
                       Bh + (size_t)n0 * 512, Bl + (size_t)n0 * 512, 512,
                       512, lds, acc);
  int lane = threadIdx.x & 63, wave = threadIdx.x >> 6;
  int lr = lane & 15, kq = lane >> 4;
  int wm = wave / WN, wn = wave % WN;
  int t = n0 >> 9;   // BN=128 tiles stay within one t
#pragma unroll
  for (int i = 0; i < 4; ++i) {
    int c = wm * 64 + 16 * i + kq * 4;
    if (c >= climit) continue;
    bool full = (c + 3) < climit;
#pragma unroll
    for (int j = 0; j < 4; ++j) {
      int jg = n0 + wn * 64 + 16 * j + lr;
      int n = jg & 511;
      size_t base = ((size_t)(b * N_ + n)) * 640 + (size_t)(1 + t) * C + cbase + c;
      f4_t v = acc[i][j];
      ushort hh[4], ll[4];
#pragma unroll
      for (int r = 0; r < 4; ++r) { hh[r] = f2bf(v[r]); ll[r] = f2bf(v[r] - bf2f(hh[r])); }
      if (full && !(base & 1)) {
        *(unsigned*)(Fh + base)     = (unsigned)hh[0] | ((unsigned)hh[1] << 16);
        *(unsigned*)(Fh + base + 2) = (unsigned)hh[2] | ((unsigned)hh[3] << 16);
        *(unsigned*)(Fl + base)     = (unsigned)ll[0] | ((unsigned)ll[1] << 16);
        *(unsigned*)(Fl + base + 2) = (unsigned)ll[2] | ((unsigned)ll[3] << 16);
      } else {
#pragma unroll
        for (int r = 0; r < 4; ++r)
          if (c + r < climit) { Fh[base + r] = hh[r]; Fl[base + r] = ll[r]; }
      }
    }
  }
}

// ---------------------------------------------------------------------------
// Gate projection: A = Wg (128 x Kpad), B = ZFT flat (32768 x Kpad, ld 640).
// Tile 128x64 (2x1 waves, 128 thr), grid 512. sigmoid; d<64 -> r*h into Zc+ZFT;
// d>=64 -> U.
// ---------------------------------------------------------------------------
__global__ __launch_bounds__(128) void projg2_k(
    const ushort* Wh, const ushort* Wl, int Kpad,
    ushort* Fh, ushort* Fl,
    const float* __restrict__ bg, const float* __restrict__ hcell,
    float* __restrict__ U, ushort* __restrict__ Zch, ushort* __restrict__ Zcl,
    int Cx) {
  __shared__ __attribute__((aligned(16))) ushort lds[2 * (2 * 128 + 2 * 64) * 32];
  int n0 = blockIdx.x * 64;
  f4_t acc[4][4] = {};
  core<128, 64, 2, 1>(Wh, Wl, Kpad,
                      Fh + (size_t)n0 * 640, Fl + (size_t)n0 * 640, 640,
                      Kpad, lds, acc);
  int lane = threadIdx.x & 63, wave = threadIdx.x >> 6;
  int lr = lane & 15, kq = lane >> 4;
  int wm = wave;   // WN=1
#pragma unroll
  for (int i = 0; i < 4; ++i) {
    int d = wm * 64 + 16 * i + kq * 4;
#pragma unroll
    for (int j = 0; j < 4; ++j) {
      int nf = n0 + 16 * j + lr;
      int b = nf >> 9, n = nf & 511;
      f4_t v = acc[i][j];
#pragma unroll
      for (int r = 0; r < 4; ++r) {
        int dd = d + r;
        float s = 1.f / (1.f + expf(-(v[r] + bg[dd])));
        if (dd < 64) {
          float rh = s * hcell[((size_t)(b << 6) + dd) * N_ + n];
          ushort hh = f2bf(rh), ll = f2bf(rh - bf2f(hh));
          size_t zi = ((size_t)(b * 128) + Cx + dd) * N_ + n;
          Zch[zi] = hh; Zcl[zi] = ll;
          size_t fi = (size_t)nf * 640 + Cx + dd;
          Fh[fi] = hh; Fl[fi] = ll;
        } else {
          U[((size_t)(b << 6) + (dd - 64)) * N_ + n] = s;
        }
      }
    }
  }
}

// ---------------------------------------------------------------------------
// Candidate projection + GRU update: A = Wc (64 x Kpad). Tile 64x64 (1 wave),
// grid 512. h = u*h + (1-u)*tanh(acc + bc).
// ---------------------------------------------------------------------------
__global__ __launch_bounds__(64) void projc2_k(
    const ushort* Wh, const ushort* Wl, int Kpad,
    const ushort* Fh, const ushort* Fl,
    const float* __restrict__ bc, const float* __restrict__ U,
    float* __restrict__ hcell) {
  __shared__ __attribute__((aligned(16))) ushort lds[2 * (2 * 64 + 2 * 64) * 32];
  int n0 = blockIdx.x * 64;
  f4_t acc[4][4] = {};
  core<64, 64, 1, 1>(Wh, Wl, Kpad,
                     Fh + (size_t)n0 * 640, Fl + (size_t)n0 * 640, 640,
                     Kpad, lds, acc);
  int lane = threadIdx.x & 63;
  int lr = lane & 15, kq = lane >> 4;
#pragma unroll
  for (int i = 0; i < 4; ++i) {
    int d = 16 * i + kq * 4;
#pragma unroll
    for (int j = 0; j < 4; ++j) {
      int nf = n0 + 16 * j + lr;
      int b = nf >> 9, n = nf & 511;
      f4_t v = acc[i][j];
#pragma unroll
      for (int r = 0; r < 4; ++r) {
        int dd = d + r;
        float ct = tanhf(v[r] + bc[dd]);
        size_t ix = ((size_t)(b << 6) + dd) * N_ + n;
        float u = U[ix];
        hcell[ix] = u * hcell[ix] + (1.f - u) * ct;
      }
    }
  }
}

__global__ __launch_bounds__(256) void proj_out_k(const float* __restrict__ h1,
                                                  const float* __restrict__ pw,
                                                  const float* __restrict__ pb,
                                                  float* __restrict__ ybuf,
                                                  float* __restrict__ out, int k) {
  int idx = blockIdx.x * blockDim.x + threadIdx.x;
  if (idx >= B_ * N_) return;
  int n = idx & 511;
  int b = idx >> 9;
  float s = pb[0];
#pragma unroll
  for (int j = 0; j < 64; ++j)
    s = fmaf(pw[j], h1[((size_t)(b << 6) + j) * N_ + n], s);
  ybuf[idx] = s;
  out[(size_t)idx * 12 + k] = s;
}

extern "C" void kernel_launch(void* const* d_in, const int* in_sizes, int n_in,
                              void* d_out, int out_size, void* d_ws, size_t ws_size,
                              hipStream_t stream) {
  const float* inputs   = (const float*)d_in[0];
  const float* supports = (const float*)d_in[1];
  const float* Wg[4] = { (const float*)d_in[2],  (const float*)d_in[6],
                         (const float*)d_in[10], (const float*)d_in[14] };
  const float* Bg[4] = { (const float*)d_in[3],  (const float*)d_in[7],
                         (const float*)d_in[11], (const float*)d_in[15] };
  const float* Wc[4] = { (const float*)d_in[4],  (const float*)d_in[8],
                         (const float*)d_in[12], (const float*)d_in[16] };
  const float* Bc[4] = { (const float*)d_in[5],  (const float*)d_in[9],
                         (const float*)d_in[13], (const float*)d_in[17] };
  const float* proj_w = (const float*)d_in[18];
  const float* proj_b = (const float*)d_in[19];
  float* out = (float*)d_out;

  char* p = (char*)d_ws;
  auto carve = [&](size_t bytes) { void* q = p; p += (bytes + 255) & ~(size_t)255; return q; };
  ushort* BmThi = (ushort*)carve((size_t)4 * N_ * N_ * 2);
  ushort* BmTlo = (ushort*)carve((size_t)4 * N_ * N_ * 2);
  ushort* Zchi  = (ushort*)carve((size_t)B_ * 128 * N_ * 2);
  ushort* Zclo  = (ushort*)carve((size_t)B_ * 128 * N_ * 2);
  ushort* ZFThi = (ushort*)carve((size_t)B_ * N_ * 640 * 2);
  ushort* ZFTlo = (ushort*)carve((size_t)B_ * N_ * 640 * 2);
  float*  U     = (float*)carve((size_t)B_ * 64 * N_ * 4);
  float*  h0    = (float*)carve((size_t)B_ * 64 * N_ * 4);
  float*  h1    = (float*)carve((size_t)B_ * 64 * N_ * 4);
  float*  ybuf  = (float*)carve((size_t)B_ * N_ * 4);
  const int CTs[4]   = { 330, 640, 325, 640 };
  const int Kpads[4] = { 352, 640, 352, 640 };
  ushort* Wth[8]; ushort* Wtl[8];
  for (int c = 0; c < 4; ++c) {
    Wth[2 * c]     = (ushort*)carve((size_t)128 * Kpads[c] * 2);
    Wtl[2 * c]     = (ushort*)carve((size_t)128 * Kpads[c] * 2);
    Wth[2 * c + 1] = (ushort*)carve((size_t)64 * Kpads[c] * 2);
    Wtl[2 * c + 1] = (ushort*)carve((size_t)64 * Kpads[c] * 2);
  }
  float* SSbuf = (float*)U;   // overlay: SS only needed during prep

  hipMemsetAsync(h0, 0, (size_t)B_ * 64 * N_ * 4, stream);
  hipMemsetAsync(h1, 0, (size_t)B_ * 64 * N_ * 4, stream);
  hipMemsetAsync(ybuf, 0, (size_t)B_ * N_ * 4, stream);

  ssq_k<<<dim3(32, 32, 2), dim3(16, 16), 0, stream>>>(supports, SSbuf);
  bmt_k<<<(4 * N_ * N_ + 255) / 256, 256, 0, stream>>>(supports, SSbuf, BmThi, BmTlo);
  for (int c = 0; c < 4; ++c) {
    wprep_k<<<(128 * Kpads[c] + 255) / 256, 256, 0, stream>>>(Wg[c], Wth[2 * c], Wtl[2 * c],
                                                              CTs[c], Kpads[c], 128);
    wprep_k<<<(64 * Kpads[c] + 255) / 256, 256, 0, stream>>>(Wc[c], Wth[2 * c + 1], Wtl[2 * c + 1],
                                                             CTs[c], Kpads[c], 64);
  }

  auto cell = [&](int ci, int Cx, const float* x, int xmode, int t, float* h) {
    int C = Cx + 64;
    int Kpad = Kpads[ci];
    pack_k<<<dim3((C + 63) / 64, 8, B_), 256, 0, stream>>>(x, xmode, t, Cx, C, h,
                                                           Zchi, Zclo, ZFThi, ZFTlo);
    // gate: diffuse all C channels of z = [x,h]
    diffg_k<2, 2><<<dim3(16, 1, B_), 256, 0, stream>>>(Zchi, Zclo, BmThi, BmTlo,
                                                       ZFThi, ZFTlo, C, 0, C);
    projg2_k<<<dim3(512, 1, 1), 128, 0, stream>>>(Wth[2 * ci], Wtl[2 * ci], Kpad,
                                                  ZFThi, ZFTlo, Bg[ci], h, U, Zchi, Zclo, Cx);
    // candidate: re-diffuse only the r*h rows (x-part features reused)
    diffg_k<1, 2><<<dim3(16, 1, B_), 128, 0, stream>>>(Zchi + (size_t)Cx * N_,
                                                       Zclo + (size_t)Cx * N_,
                                                       BmThi, BmTlo, ZFThi, ZFTlo, C, Cx, 64);
    projc2_k<<<dim3(512, 1, 1), 64, 0, stream>>>(Wth[2 * ci + 1], Wtl[2 * ci + 1], Kpad,
                                                 ZFThi, ZFTlo, Bc[ci], U, h);
  };

  for (int t = 0; t < 12; ++t) {
    cell(0, 2, inputs, 0, t, h0);
    cell(1, 64, h0, 1, 0, h1);
  }
  for (int k = 0; k < 12; ++k) {
    cell(2, 1, ybuf, 1, 0, h0);
    cell(3, 64, h0, 1, 0, h1);
    proj_out_k<<<(B_ * N_ + 255) / 256, 256, 0, stream>>>(h1, proj_w, proj_b, ybuf, out, k);
  }
}

// Round 4
// 13740.810 us; speedup vs baseline: 2.2747x; 1.1471x over previous
//
#include <hip/hip_runtime.h>

#define B_ 64
#define N_ 512

typedef __attribute__((ext_vector_type(8))) short bf8_t;   // 8 bf16 (4 VGPRs)
typedef __attribute__((ext_vector_type(4))) float f4_t;    // MFMA accumulator

#define MFMA(a, b, c) __builtin_amdgcn_mfma_f32_16x16x32_bf16(a, b, c, 0, 0, 0)

__device__ __forceinline__ ushort f2bf(float x) {
  union { float f; unsigned u; } v; v.f = x;
  unsigned r = v.u + 0x7FFFu + ((v.u >> 16) & 1u);   // RNE
  return (ushort)(r >> 16);
}
__device__ __forceinline__ float bf2f(ushort h) {
  union { unsigned u; float f; } v; v.u = ((unsigned)h) << 16;
  return v.f;
}

__device__ __forceinline__ void gld16(const ushort* g, ushort* l) {
  __builtin_amdgcn_global_load_lds(
      (const __attribute__((address_space(1))) unsigned int*)(uintptr_t)g,
      (__attribute__((address_space(3))) unsigned int*)(uintptr_t)l,
      16, 0, 0);
}

// XOR swizzle (BK=32: 4x 16B slots/row, spread via (r>>1)&3 → 2-way = free)
__device__ __forceinline__ int swz32(int r) { return (r >> 1) & 3; }

// Stage one (ROWS x 32) bf16 tile into LDS, 16B/lane, source pre-swizzled.
template <int ROWS>
__device__ __forceinline__ void stage_tile(const ushort* gbase, int lda, int koff,
                                           ushort* ldst, int tid) {
  constexpr int RT = ROWS / 64;   // rounds (each round = 256 thr * 8 ushorts = 4KB)
#pragma unroll
  for (int q = 0; q < RT; ++q) {
    int e  = q * 2048 + tid * 8;
    int r  = e >> 5;              // row within tile
    int c8 = (e >> 3) & 3;        // 16B slot
    int g8 = c8 ^ swz32(r);       // pre-swizzled source slot
    gld16(gbase + (size_t)r * lda + koff + g8 * 8, ldst + e);
  }
}

// ---------------------------------------------------------------------------
// Split-bf16 GEMM core: C[m][n] = sum_k A[m][k]*B[n][k], both K-contiguous.
// 128x128 tile, BK=32, double-buffered 64KB LDS via global_load_lds,
// 3-term MFMA (AhBh + AhBl + AlBh). A may be K-segmented (SEGK, segStrideA).
// ---------------------------------------------------------------------------
template <int SEGK>
__device__ __forceinline__ void core128(
    const ushort* Ah, const ushort* Al, int lda, int segStrideA,
    const ushort* Bh, const ushort* Bl, int ldb,
    int K, ushort* lds, f4_t acc[4][4], int wm, int wn, int lr, int kq) {
  constexpr int TILE = 128 * 32;            // ushorts per half-operand tile
  constexpr int SSZ  = 4 * TILE;            // per stage buffer
  const int tid = threadIdx.x;

  auto stage = [&](int buf, int k0) {
    int seg = k0 / SEGK;
    int koffA = seg * segStrideA + (k0 & (SEGK - 1));
    ushort* lb = lds + buf * SSZ;
    stage_tile<128>(Ah, lda, koffA, lb, tid);
    stage_tile<128>(Al, lda, koffA, lb + TILE, tid);
    stage_tile<128>(Bh, ldb, k0, lb + 2 * TILE, tid);
    stage_tile<128>(Bl, ldb, k0, lb + 3 * TILE, tid);
  };

  const int nc = K >> 5;
  stage(0, 0);
  int buf = 0;
  for (int c = 0; c < nc; ++c) {
    __syncthreads();
    if (c + 1 < nc) stage(buf ^ 1, (c + 1) << 5);
    const ushort* lb = lds + buf * SSZ;
    bf8_t ah[4], al[4], bh[4], bl[4];
#pragma unroll
    for (int i = 0; i < 4; ++i) {
      int r = wm * 64 + 16 * i + lr;
      int c8 = kq ^ swz32(r);
      ah[i] = *(const bf8_t*)(lb + r * 32 + c8 * 8);
      al[i] = *(const bf8_t*)(lb + TILE + r * 32 + c8 * 8);
    }
#pragma unroll
    for (int j = 0; j < 4; ++j) {
      int r = wn * 64 + 16 * j + lr;
      int c8 = kq ^ swz32(r);
      bh[j] = *(const bf8_t*)(lb + 2 * TILE + r * 32 + c8 * 8);
      bl[j] = *(const bf8_t*)(lb + 3 * TILE + r * 32 + c8 * 8);
    }
#pragma unroll
    for (int i = 0; i < 4; ++i)
#pragma unroll
      for (int j = 0; j < 4; ++j) {
        acc[i][j] = MFMA(ah[i], bh[j], acc[i][j]);
        acc[i][j] = MFMA(ah[i], bl[j], acc[i][j]);
        acc[i][j] = MFMA(al[i], bh[j], acc[i][j]);
      }
    buf ^= 1;
  }
}

// ---------------------------------------------------------------------------
// Prep: SS[s] = S[s]^2 (f32)
// ---------------------------------------------------------------------------
__global__ __launch_bounds__(256) void ssq_k(const float* __restrict__ S,
                                             float* __restrict__ SS) {
  int s = blockIdx.z;
  const float* Ss = S + s * N_ * N_;
  __shared__ float Ta[16][17], Tb[16][17];
  int n = blockIdx.y * 16 + threadIdx.y;
  int m = blockIdx.x * 16 + threadIdx.x;
  float acc = 0.f;
  for (int p0 = 0; p0 < N_; p0 += 16) {
    Ta[threadIdx.y][threadIdx.x] = Ss[n * N_ + p0 + threadIdx.x];
    Tb[threadIdx.y][threadIdx.x] = Ss[(p0 + threadIdx.y) * N_ + m];
    __syncthreads();
#pragma unroll
    for (int pp = 0; pp < 16; ++pp)
      acc = fmaf(Ta[threadIdx.y][pp], Tb[pp][threadIdx.x], acc);
    __syncthreads();
  }
  SS[((size_t)s * N_ + n) * N_ + m] = acc;
}

// BcatT[n][k], k = seg*512+m, segs [S0, S0^2, S1, S1^2], split hi/lo
__global__ __launch_bounds__(256) void bcat_k(const float* __restrict__ S,
                                              const float* __restrict__ SS,
                                              ushort* __restrict__ Bh,
                                              ushort* __restrict__ Bl) {
  int idx = blockIdx.x * 256 + threadIdx.x;
  if (idx >= 512 * 2048) return;
  int k = idx & 2047, n = idx >> 11;
  int seg = k >> 9, m = k & 511;
  float v;
  if (seg == 0)      v = S[(size_t)n * 512 + m];
  else if (seg == 1) v = SS[(size_t)n * 512 + m];
  else if (seg == 2) v = S[(size_t)(512 + n) * 512 + m];
  else               v = SS[(size_t)(512 + n) * 512 + m];
  ushort hh = f2bf(v);
  Bh[idx] = hh; Bl[idx] = f2bf(v - bf2f(hh));
}

// Wt[i = t*Dout + d][c] (128-wide rows) from W[(t*C+c)*Dout + d]; zeros outside
__global__ __launch_bounds__(256) void wprep2_k(const float* __restrict__ W,
                                                ushort* __restrict__ Wh,
                                                ushort* __restrict__ Wl,
                                                int C, int Dout, int Mt) {
  int idx = blockIdx.x * 256 + threadIdx.x;
  if (idx >= Mt * 128) return;
  int c = idx & 127, i = idx >> 7;
  int t = i / Dout, d = i % Dout;
  float v = (c < C && t < 5) ? W[(size_t)(t * C + c) * Dout + d] : 0.f;
  ushort hh = f2bf(v);
  Wh[idx] = hh; Wl[idx] = f2bf(v - bf2f(hh));
}

// ---------------------------------------------------------------------------
// Pack zT[(b,n)][c] = [x | h | 0-pad], split hi/lo. 1 thread per (b,n) row.
// ---------------------------------------------------------------------------
__global__ __launch_bounds__(256) void packzT_k(const float* __restrict__ xsrc,
                                                int xmode, int t, int Cx, int C,
                                                const float* __restrict__ h,
                                                ushort* __restrict__ Zh,
                                                ushort* __restrict__ Zl) {
  int jg = blockIdx.x * 256 + threadIdx.x;   // b*512 + n
  int b = jg >> 9, n = jg & 511;
  for (int c0 = 0; c0 < 128; c0 += 8) {
    bf8_t vh, vl;
#pragma unroll
    for (int q = 0; q < 8; ++q) {
      int c = c0 + q;
      float v;
      if (c < Cx) v = (xmode == 0) ? xsrc[((size_t)(b * Cx + c) * 512 + n) * 12 + t]
                                   : xsrc[(size_t)(b * Cx + c) * 512 + n];
      else if (c < C) v = h[((size_t)b * 64 + (c - Cx)) * 512 + n];
      else v = 0.f;
      ushort hh = f2bf(v);
      vh[q] = (short)hh;
      vl[q] = (short)f2bf(v - bf2f(hh));
    }
    *(bf8_t*)(Zh + (size_t)jg * 128 + c0) = vh;
    *(bf8_t*)(Zl + (size_t)jg * 128 + c0) = vl;
  }
}

// ---------------------------------------------------------------------------
// Step 1: G = Wt * zT^T.  A = Wt (Mt x 128-ld), B = zT (32768 x 128-ld), K=K1.
// MODE 0 (gate):  G[b][t][d(128)][m]  at ((b*5+t)*128+d)*512+m
// MODE 1 (cand):  G[t][b*64+d][m]     at (t*4096 + b*64+d)*512+m
// ---------------------------------------------------------------------------
template <int MODE>
__global__ __launch_bounds__(256) void g1_k(const ushort* __restrict__ Wh,
                                            const ushort* __restrict__ Wl,
                                            const ushort* __restrict__ Zh,
                                            const ushort* __restrict__ Zl,
                                            ushort* __restrict__ Gh,
                                            ushort* __restrict__ Gl,
                                            int K, int Mlimit) {
  __shared__ __attribute__((aligned(16))) ushort lds[2 * 4 * 128 * 32];
  int tid = threadIdx.x, lane = tid & 63, wave = tid >> 6;
  int wm = wave >> 1, wn = wave & 1, lr = lane & 15, kq = lane >> 4;
  int nt = blockIdx.x, mt = blockIdx.y;
  f4_t acc[4][4] = {};
  core128<(1 << 28)>(Wh + (size_t)mt * 128 * 128, Wl + (size_t)mt * 128 * 128, 128, 0,
                     Zh + (size_t)nt * 128 * 128, Zl + (size_t)nt * 128 * 128, 128,
                     K, lds, acc, wm, wn, lr, kq);
#pragma unroll
  for (int i = 0; i < 4; ++i) {
    int ii0 = mt * 128 + wm * 64 + 16 * i + kq * 4;
    if (ii0 >= Mlimit) continue;
#pragma unroll
    for (int j = 0; j < 4; ++j) {
      int jg = nt * 128 + wn * 64 + 16 * j + lr;
      int b = jg >> 9, m = jg & 511;
      f4_t v = acc[i][j];
#pragma unroll
      for (int r = 0; r < 4; ++r) {
        int ii = ii0 + r;
        if (ii >= Mlimit) break;
        size_t addr;
        if (MODE == 0)
          addr = ((size_t)(b * 5 + (ii >> 7)) * 128 + (ii & 127)) * 512 + m;
        else
          addr = ((size_t)(ii >> 6) * 4096 + (size_t)(b * 64 + (ii & 63))) * 512 + m;
        ushort hh = f2bf(v[r]);
        Gh[addr] = hh; Gl[addr] = f2bf(v[r] - bf2f(hh));
      }
    }
  }
}

// ---------------------------------------------------------------------------
// Step 2 gate: RU[(b,d)][n] = sum_seg G_seg * BcatT + G0 + bg -> sigmoid.
// d<64: write r*h into zT cols [Cx,Cx+64); d>=64: u -> U.
// grid (4 n-tiles, 64 b)
// ---------------------------------------------------------------------------
__global__ __launch_bounds__(256) void ru1_k(const ushort* __restrict__ Gh,
                                             const ushort* __restrict__ Gl,
                                             const ushort* __restrict__ Bch,
                                             const ushort* __restrict__ Bcl,
                                             const float* __restrict__ bg,
                                             const float* __restrict__ h,
                                             float* __restrict__ U,
                                             ushort* __restrict__ Zh,
                                             ushort* __restrict__ Zl, int Cx) {
  __shared__ __attribute__((aligned(16))) ushort lds[2 * 4 * 128 * 32];
  int tid = threadIdx.x, lane = tid & 63, wave = tid >> 6;
  int wm = wave >> 1, wn = wave & 1, lr = lane & 15, kq = lane >> 4;
  int nt = blockIdx.x, b = blockIdx.y;
  const size_t gb = (size_t)b * 5 * 128 * 512;
  f4_t acc[4][4] = {};
  core128<512>(Gh + gb + 65536, Gl + gb + 65536, 512, 65536,
               Bch + (size_t)nt * 128 * 2048, Bcl + (size_t)nt * 128 * 2048, 2048,
               2048, lds, acc, wm, wn, lr, kq);
#pragma unroll
  for (int i = 0; i < 4; ++i) {
    int d0 = wm * 64 + 16 * i + kq * 4;
#pragma unroll
    for (int j = 0; j < 4; ++j) {
      int n = nt * 128 + wn * 64 + 16 * j + lr;
      f4_t v = acc[i][j];
#pragma unroll
      for (int r = 0; r < 4; ++r) {
        int d = d0 + r;
        size_t g0 = gb + (size_t)d * 512 + n;
        float s = v[r] + bf2f(Gh[g0]) + bf2f(Gl[g0]) + bg[d];
        s = 1.f / (1.f + expf(-s));
        if (d < 64) {
          float rh = s * h[((size_t)b * 64 + d) * 512 + n];
          ushort hh = f2bf(rh);
          size_t zi = (size_t)(b * 512 + n) * 128 + Cx + d;
          Zh[zi] = hh; Zl[zi] = f2bf(rh - bf2f(hh));
        } else {
          U[((size_t)b * 64 + (d - 64)) * 512 + n] = s;
        }
      }
    }
  }
}

// ---------------------------------------------------------------------------
// Step 2 cand: c~ = tanh(sum_seg Gc_seg * BcatT + Gc0 + bc); h = u*h + (1-u)*c~
// Row rg = b*64+d (4096 rows). grid (4 n-tiles, 32 row-tiles)
// ---------------------------------------------------------------------------
__global__ __launch_bounds__(256) void ru2_k(const ushort* __restrict__ Gh,
                                             const ushort* __restrict__ Gl,
                                             const ushort* __restrict__ Bch,
                                             const ushort* __restrict__ Bcl,
                                             const float* __restrict__ bc,
                                             const float* __restrict__ U,
                                             float* __restrict__ h) {
  __shared__ __attribute__((aligned(16))) ushort lds[2 * 4 * 128 * 32];
  int tid = threadIdx.x, lane = tid & 63, wave = tid >> 6;
  int wm = wave >> 1, wn = wave & 1, lr = lane & 15, kq = lane >> 4;
  int nt = blockIdx.x, mt = blockIdx.y;
  f4_t acc[4][4] = {};
  core128<512>(Gh + (size_t)4096 * 512 + (size_t)mt * 128 * 512,
               Gl + (size_t)4096 * 512 + (size_t)mt * 128 * 512, 512, 4096 * 512,
               Bch + (size_t)nt * 128 * 2048, Bcl + (size_t)nt * 128 * 2048, 2048,
               2048, lds, acc, wm, wn, lr, kq);
#pragma unroll
  for (int i = 0; i < 4; ++i) {
    int rg0 = mt * 128 + wm * 64 + 16 * i + kq * 4;
#pragma unroll
    for (int j = 0; j < 4; ++j) {
      int n = nt * 128 + wn * 64 + 16 * j + lr;
      f4_t v = acc[i][j];
#pragma unroll
      for (int r = 0; r < 4; ++r) {
        int rg = rg0 + r;
        size_t ix = (size_t)rg * 512 + n;
        float ct = v[r] + bf2f(Gh[ix]) + bf2f(Gl[ix]) + bc[rg & 63];
        ct = tanhf(ct);
        float u = U[ix];
        h[ix] = u * h[ix] + (1.f - u) * ct;
      }
    }
  }
}

__global__ __launch_bounds__(256) void proj_out_k(const float* __restrict__ h1,
                                                  const float* __restrict__ pw,
                                                  const float* __restrict__ pb,
                                                  float* __restrict__ ybuf,
                                                  float* __restrict__ out, int k) {
  int idx = blockIdx.x * blockDim.x + threadIdx.x;
  if (idx >= B_ * N_) return;
  float s = pb[0];
#pragma unroll
  for (int j = 0; j < 64; ++j)
    s = fmaf(pw[j], h1[(size_t)((idx >> 9) * 64 + j) * 512 + (idx & 511)], s);
  ybuf[idx] = s;
  out[(size_t)idx * 12 + k] = s;
}

extern "C" void kernel_launch(void* const* d_in, const int* in_sizes, int n_in,
                              void* d_out, int out_size, void* d_ws, size_t ws_size,
                              hipStream_t stream) {
  const float* inputs   = (const float*)d_in[0];
  const float* supports = (const float*)d_in[1];
  const float* Wg[4] = { (const float*)d_in[2],  (const float*)d_in[6],
                         (const float*)d_in[10], (const float*)d_in[14] };
  const float* Bg[4] = { (const float*)d_in[3],  (const float*)d_in[7],
                         (const float*)d_in[11], (const float*)d_in[15] };
  const float* Wc[4] = { (const float*)d_in[4],  (const float*)d_in[8],
                         (const float*)d_in[12], (const float*)d_in[16] };
  const float* Bc[4] = { (const float*)d_in[5],  (const float*)d_in[9],
                         (const float*)d_in[13], (const float*)d_in[17] };
  const float* proj_w = (const float*)d_in[18];
  const float* proj_b = (const float*)d_in[19];
  float* out = (float*)d_out;

  char* p = (char*)d_ws;
  auto carve = [&](size_t bytes) { void* q = p; p += (bytes + 255) & ~(size_t)255; return q; };
  ushort* Bch = (ushort*)carve((size_t)512 * 2048 * 2);
  ushort* Bcl = (ushort*)carve((size_t)512 * 2048 * 2);
  ushort* zTh = (ushort*)carve((size_t)32768 * 128 * 2);
  ushort* zTl = (ushort*)carve((size_t)32768 * 128 * 2);
  ushort* Gh  = (ushort*)carve((size_t)64 * 5 * 128 * 512 * 2);   // 42 MB
  ushort* Gl  = (ushort*)carve((size_t)64 * 5 * 128 * 512 * 2);
  float*  U   = (float*)carve((size_t)4096 * 512 * 4);
  float*  h0  = (float*)carve((size_t)4096 * 512 * 4);
  float*  h1  = (float*)carve((size_t)4096 * 512 * 4);
  float*  ybuf = (float*)carve((size_t)B_ * N_ * 4);
  ushort* Wgh[4]; ushort* Wgl[4]; ushort* Wch[4]; ushort* Wcl[4];
  for (int c = 0; c < 4; ++c) {
    Wgh[c] = (ushort*)carve((size_t)640 * 128 * 2);
    Wgl[c] = (ushort*)carve((size_t)640 * 128 * 2);
    Wch[c] = (ushort*)carve((size_t)384 * 128 * 2);
    Wcl[c] = (ushort*)carve((size_t)384 * 128 * 2);
  }
  float* SSbuf = (float*)U;   // overlay: SS only needed during prep

  hipMemsetAsync(h0, 0, (size_t)4096 * 512 * 4, stream);
  hipMemsetAsync(h1, 0, (size_t)4096 * 512 * 4, stream);
  hipMemsetAsync(ybuf, 0, (size_t)B_ * N_ * 4, stream);

  ssq_k<<<dim3(32, 32, 2), dim3(16, 16), 0, stream>>>(supports, SSbuf);
  bcat_k<<<(512 * 2048 + 255) / 256, 256, 0, stream>>>(supports, SSbuf, Bch, Bcl);
  const int Cs[4] = { 66, 128, 65, 128 };
  for (int c = 0; c < 4; ++c) {
    wprep2_k<<<(640 * 128 + 255) / 256, 256, 0, stream>>>(Wg[c], Wgh[c], Wgl[c], Cs[c], 128, 640);
    wprep2_k<<<(384 * 128 + 255) / 256, 256, 0, stream>>>(Wc[c], Wch[c], Wcl[c], Cs[c], 64, 384);
  }

  auto cell = [&](int ci, int Cx, const float* x, int xmode, int t, float* h) {
    int C = Cx + 64;
    int K1 = (C + 31) & ~31;   // 96 or 128
    packzT_k<<<128, 256, 0, stream>>>(x, xmode, t, Cx, C, h, zTh, zTl);
    g1_k<0><<<dim3(256, 5), 256, 0, stream>>>(Wgh[ci], Wgl[ci], zTh, zTl, Gh, Gl, K1, 640);
    ru1_k<<<dim3(4, 64), 256, 0, stream>>>(Gh, Gl, Bch, Bcl, Bg[ci], h, U, zTh, zTl, Cx);
    g1_k<1><<<dim3(256, 3), 256, 0, stream>>>(Wch[ci], Wcl[ci], zTh, zTl, Gh, Gl, K1, 320);
    ru2_k<<<dim3(4, 32), 256, 0, stream>>>(Gh, Gl, Bch, Bcl, Bc[ci], U, h);
  };

  for (int t = 0; t < 12; ++t) {
    cell(0, 2, inputs, 0, t, h0);
    cell(1, 64, h0, 1, 0, h1);
  }
  for (int k = 0; k < 12; ++k) {
    cell(2, 1, ybuf, 1, 0, h0);
    cell(3, 64, h0, 1, 0, h1);
    proj_out_k<<<(B_ * N_ + 255) / 256, 256, 0, stream>>>(h1, proj_w, proj_b, ybuf, out, k);
  }
}